// Round 1
// baseline (240.499 us; speedup 1.0000x reference)
//
#include <hip/hip_runtime.h>
#include <math.h>

#define BB 4
#define CC 64
#define IH 192
#define IW 192
#define OH 384
#define OW 384
#define NE 4
#define NR 4
#define HID 64

__device__ __forceinline__ float gelu_exact(float v) {
    return 0.5f * v * (1.0f + erff(v * 0.70710678118654752f));
}

// ws layout (floats):
//   [0    .. 1023] : wcT[parity][c][r]   (parity = (oy&1)*2 + (ox&1))
//   [1024 .. 2047] : weT[parity][c][r]
//   [2048 .. 2055] : offset[parity][2]   (x, y)
__global__ void precompute_kernel(
    const float* __restrict__ wcomp, const float* __restrict__ wexp,
    const float* __restrict__ bw1, const float* __restrict__ bb1,
    const float* __restrict__ bw2, const float* __restrict__ bb2,
    const float* __restrict__ rw, const float* __restrict__ rb,
    const float* __restrict__ ow, const float* __restrict__ ob,
    float* __restrict__ ws)
{
    __shared__ float s_e1[4][HID];
    __shared__ float s_e2[4][HID];
    __shared__ float s_rt[4][NE];
    const int tid = threadIdx.x;
    const int p = tid >> 6;      // parity 0..3
    const int j = tid & 63;
    // feat = [1/scale_w, 1/scale_h, coor_h, coor_w]; scale = 2 exactly =>
    // coor = -0.25 (even) / +0.25 (odd). p bit1 = oy parity, bit0 = ox parity.
    const float ch = (p & 2) ? 0.25f : -0.25f;
    const float cw = (p & 1) ? 0.25f : -0.25f;
    float a = bw1[j*4+0]*0.5f + bw1[j*4+1]*0.5f + bw1[j*4+2]*ch + bw1[j*4+3]*cw + bb1[j];
    s_e1[p][j] = gelu_exact(a);
    __syncthreads();
    float acc = bb2[j];
    #pragma unroll 8
    for (int k = 0; k < HID; ++k) acc += bw2[j*HID+k]*s_e1[p][k];
    s_e2[p][j] = gelu_exact(acc);
    __syncthreads();
    if (j < NE) {
        float s = rb[j];
        for (int k = 0; k < HID; ++k) s += rw[j*HID+k]*s_e2[p][k];
        s_rt[p][j] = 1.0f/(1.0f+expf(-s));
    } else if (j < NE+2) {
        const int d = j - NE;
        float s = ob[d];
        for (int k = 0; k < HID; ++k) s += ow[d*HID+k]*s_e2[p][k];
        ws[2048 + p*2 + d] = s;
    }
    __syncthreads();
    const int c = j;
    const float r0 = s_rt[p][0], r1 = s_rt[p][1], r2 = s_rt[p][2], r3 = s_rt[p][3];
    #pragma unroll
    for (int r = 0; r < NR; ++r) {
        // wc[r][c] = sum_e rout[e] * weight_compress[e, r, c]  (stored transposed [c][r])
        float v = r0*wcomp[0*NR*CC + r*CC + c] + r1*wcomp[1*NR*CC + r*CC + c]
                + r2*wcomp[2*NR*CC + r*CC + c] + r3*wcomp[3*NR*CC + r*CC + c];
        ws[(p*CC + c)*4 + r] = v;
        // we[c][r] = sum_e rout[e] * weight_expand[e, c, r]
        float u = r0*wexp[0*CC*NR + c*NR + r] + r1*wexp[1*CC*NR + c*NR + r]
                + r2*wexp[2*CC*NR + c*NR + r] + r3*wexp[3*CC*NR + c*NR + r];
        ws[1024 + (p*CC + c)*4 + r] = u;
    }
}

__global__ __launch_bounds__(256, 4) void upsample_kernel(
    const float* __restrict__ x, const float* __restrict__ ws,
    float* __restrict__ out)
{
    __shared__ __align__(16) float s_tab[2056];
    for (int i = threadIdx.x; i < 2056; i += 256) s_tab[i] = ws[i];
    __syncthreads();

    const int idx = blockIdx.x * 256 + threadIdx.x;
    const int b   = idx / (OH*OW);
    const int rem = idx - b*(OH*OW);
    const int oy  = rem / OW;
    const int ox  = rem - oy*OW;
    const int p   = ((oy & 1) << 1) | (ox & 1);

    const float offx = s_tab[2048 + p*2 + 0];
    const float offy = s_tab[2048 + p*2 + 1];

    const float inv_w1 = 2.0f / 191.0f;   // 2/(w-1), h==w==192
    float gx2 = (((ox + 0.5f)*0.5f - 0.5f) * inv_w1 - 1.0f) + offx * inv_w1;
    float gy2 = (((oy + 0.5f)*0.5f - 0.5f) * inv_w1 - 1.0f) + offy * inv_w1;
    float ix = (gx2 + 1.0f) * 96.0f - 0.5f;   // (g+1)*w/2 - 0.5
    float iy = (gy2 + 1.0f) * 96.0f - 0.5f;

    float x0f = floorf(ix), y0f = floorf(iy);
    float wx1 = ix - x0f, wx0 = 1.0f - wx1;
    float wy1 = iy - y0f, wy0 = 1.0f - wy1;
    float x1f = x0f + 1.0f, y1f = y0f + 1.0f;
    // zero-padding validity folded into the 4 bilinear weights
    float vx0 = (x0f >= 0.0f && x0f <= 191.0f) ? 1.0f : 0.0f;
    float vx1 = (x1f >= 0.0f && x1f <= 191.0f) ? 1.0f : 0.0f;
    float vy0 = (y0f >= 0.0f && y0f <= 191.0f) ? 1.0f : 0.0f;
    float vy1 = (y1f >= 0.0f && y1f <= 191.0f) ? 1.0f : 0.0f;
    const float w00 = wy0*wx0*vy0*vx0;
    const float w01 = wy0*wx1*vy0*vx1;
    const float w10 = wy1*wx0*vy1*vx0;
    const float w11 = wy1*wx1*vy1*vx1;

    const int xi0 = (int)fminf(fmaxf(x0f, 0.0f), 191.0f);
    const int xi1 = (int)fminf(fmaxf(x1f, 0.0f), 191.0f);
    const int yi0 = (int)fminf(fmaxf(y0f, 0.0f), 191.0f);
    const int yi1 = (int)fminf(fmaxf(y1f, 0.0f), 191.0f);

    const float* __restrict__ xb = x + (size_t)b * (CC*IH*IW);
    const int o00 = yi0*IW + xi0;
    const int o01 = yi0*IW + xi1;
    const int o10 = yi1*IW + xi0;
    const int o11 = yi1*IW + xi1;

    const float4* wc4 = ((const float4*)s_tab) + p*CC;        // wcT[p][c][0..3]
    const float4* we4 = ((const float4*)s_tab) + 256 + p*CC;  // weT[p][c][0..3]

    float f[CC];
    float mid0 = 0.f, mid1 = 0.f, mid2 = 0.f, mid3 = 0.f;
    #pragma unroll
    for (int c = 0; c < CC; ++c) {
        const int o = c*IH*IW;
        float v = w00*xb[o+o00] + w01*xb[o+o01] + w10*xb[o+o10] + w11*xb[o+o11];
        f[c] = v;
        float4 wc = wc4[c];
        mid0 += wc.x*v; mid1 += wc.y*v; mid2 += wc.z*v; mid3 += wc.w*v;
    }
    float* __restrict__ op = out + (size_t)b * (CC*OH*OW) + oy*OW + ox;
    #pragma unroll
    for (int c = 0; c < CC; ++c) {
        float4 we = we4[c];
        op[c*OH*OW] = f[c] + we.x*mid0 + we.y*mid1 + we.z*mid2 + we.w*mid3;
    }
}

extern "C" void kernel_launch(void* const* d_in, const int* in_sizes, int n_in,
                              void* d_out, int out_size, void* d_ws, size_t ws_size,
                              hipStream_t stream) {
    const float* x     = (const float*)d_in[0];
    const float* wcomp = (const float*)d_in[1];
    const float* wexp  = (const float*)d_in[2];
    const float* bw1   = (const float*)d_in[3];
    const float* bb1   = (const float*)d_in[4];
    const float* bw2   = (const float*)d_in[5];
    const float* bb2   = (const float*)d_in[6];
    const float* rw    = (const float*)d_in[7];
    const float* rb    = (const float*)d_in[8];
    const float* ow    = (const float*)d_in[9];
    const float* ob    = (const float*)d_in[10];
    float* ws  = (float*)d_ws;
    float* out = (float*)d_out;

    precompute_kernel<<<1, 256, 0, stream>>>(wcomp, wexp, bw1, bb1, bw2, bb2,
                                             rw, rb, ow, ob, ws);
    const int total = BB*OH*OW;            // 589824, exact multiple of 256
    upsample_kernel<<<total/256, 256, 0, stream>>>(x, ws, out);
}